// Round 4
// baseline (751.980 us; speedup 1.0000x reference)
//
#include <hip/hip_runtime.h>
#include <hip/hip_fp16.h>
#include <math.h>

#define ITERS 12

typedef __attribute__((ext_vector_type(8))) short short8;
typedef __attribute__((ext_vector_type(4))) float float4v;

static __device__ inline unsigned short f2bf(float f) {
    union { float f; unsigned int u; } c; c.f = f;
    unsigned int u = c.u;
    u += 0x7fffu + ((u >> 16) & 1u);          // round-to-nearest-even
    return (unsigned short)(u >> 16);
}
static __device__ inline float bf2f(unsigned short h) {
    union { float f; unsigned int u; } c; c.u = ((unsigned int)h) << 16;
    return c.f;
}

// ---------------------------------------------------------------------------
// Kernel A (unchanged): P = l2_normalize(X @ W^T + b), emitted as split-bf16
// rows of 192:
//   sub:  [hi(64) | lo(64) | hi(64)]
//   edge: [hi(64) | hi(64) | lo(64)]
// so that subE @ edgeE^T over K=192 = Ah*Bh + Al*Bh + Ah*Bl (lo*lo dropped).
// ---------------------------------------------------------------------------
__global__ __launch_bounds__(256) void proj_norm_kernel(
    const float* __restrict__ Xsub, const float* __restrict__ Xedge,
    const float* __restrict__ Wsub, const float* __restrict__ bsub,
    const float* __restrict__ Wedge, const float* __restrict__ bedge,
    unsigned short* __restrict__ subE, unsigned short* __restrict__ edgeE)
{
    const int mat = blockIdx.y;
    const float* X  = mat ? Xedge : Xsub;
    const float* W  = mat ? Wedge : Wsub;
    const float* Bv = mat ? bedge : bsub;
    unsigned short* OUT = mat ? edgeE : subE;

    const int r0 = blockIdx.x * 32;
    const int t  = threadIdx.x;
    const int tx = t & 15, ty = t >> 4;

    __shared__ float xs[64 * 34];   // [k][row(32)+pad]
    __shared__ float ws[64 * 68];   // [k][col(64)+pad]

    float acc[2][4] = {};

    for (int ch = 0; ch < 8; ++ch) {
        const int kb = ch * 64;
#pragma unroll
        for (int i = 0; i < 2; ++i) {
            int e = t + 256 * i;            // 512 float4 (32 rows x 16 kq)
            int row = e & 31, kq = e >> 5;
            float4 xv = *(const float4*)(X + (size_t)(r0 + row) * 512 + kb + kq * 4);
            xs[(kq * 4 + 0) * 34 + row] = xv.x;
            xs[(kq * 4 + 1) * 34 + row] = xv.y;
            xs[(kq * 4 + 2) * 34 + row] = xv.z;
            xs[(kq * 4 + 3) * 34 + row] = xv.w;
        }
#pragma unroll
        for (int i = 0; i < 4; ++i) {
            int e = t + 256 * i;            // 1024 float4 (64 cols x 16 kq)
            int col = e & 63, kq = e >> 6;
            float4 wv = *(const float4*)(W + (size_t)col * 512 + kb + kq * 4);
            ws[(kq * 4 + 0) * 68 + col] = wv.x;
            ws[(kq * 4 + 1) * 68 + col] = wv.y;
            ws[(kq * 4 + 2) * 68 + col] = wv.z;
            ws[(kq * 4 + 3) * 68 + col] = wv.w;
        }
        __syncthreads();
#pragma unroll 8
        for (int k = 0; k < 64; ++k) {
            const float2 a2 = *(const float2*)&xs[k * 34 + ty * 2];
            const float4 b4 = *(const float4*)&ws[k * 68 + tx * 4];
            acc[0][0] = fmaf(a2.x, b4.x, acc[0][0]);
            acc[0][1] = fmaf(a2.x, b4.y, acc[0][1]);
            acc[0][2] = fmaf(a2.x, b4.z, acc[0][2]);
            acc[0][3] = fmaf(a2.x, b4.w, acc[0][3]);
            acc[1][0] = fmaf(a2.y, b4.x, acc[1][0]);
            acc[1][1] = fmaf(a2.y, b4.y, acc[1][1]);
            acc[1][2] = fmaf(a2.y, b4.z, acc[1][2]);
            acc[1][3] = fmaf(a2.y, b4.w, acc[1][3]);
        }
        __syncthreads();
    }

    const float4 bb = *(const float4*)(Bv + tx * 4);
#pragma unroll
    for (int i = 0; i < 2; ++i) {
        acc[i][0] += bb.x; acc[i][1] += bb.y; acc[i][2] += bb.z; acc[i][3] += bb.w;
        float s = acc[i][0]*acc[i][0] + acc[i][1]*acc[i][1]
                + acc[i][2]*acc[i][2] + acc[i][3]*acc[i][3];
#pragma unroll
        for (int off = 1; off <= 8; off <<= 1)
            s += __shfl_xor(s, off, 64);
        const float inv = 1.0f / fmaxf(sqrtf(s), 1e-12f);

        unsigned short h[4], l[4];
#pragma unroll
        for (int j = 0; j < 4; ++j) {
            const float v = acc[i][j] * inv;
            h[j] = f2bf(v);
            l[j] = f2bf(v - bf2f(h[j]));
        }
        uint2 hp, lp;
        hp.x = (unsigned)h[0] | ((unsigned)h[1] << 16);
        hp.y = (unsigned)h[2] | ((unsigned)h[3] << 16);
        lp.x = (unsigned)l[0] | ((unsigned)l[1] << 16);
        lp.y = (unsigned)l[2] | ((unsigned)l[3] << 16);

        unsigned short* base = OUT + (size_t)(r0 + ty * 2 + i) * 192 + tx * 4;
        *(uint2*)(base)       = hp;
        *(uint2*)(base + 64)  = mat ? hp : lp;   // edge: hi ; sub: lo
        *(uint2*)(base + 128) = mat ? lp : hp;   // edge: lo ; sub: hi
    }
}

// ---------------------------------------------------------------------------
// Kernel F (v3): FUSED scores + entmax.  Identical algorithm to v2; the only
// change is the occupancy pin: amdgpu_waves_per_eu(4,4) so the register
// allocator targets EXACTLY 4 waves/EU (one 16-wave block per CU) and uses
// the full 128-VGPR budget.  v2's __launch_bounds__(1024,4) only set a
// MINIMUM of 4 waves/EU, so the allocator shrank to 64 VGPR to fit 8
// waves/EU and spilled zh[64] to scratch (counters: VGPR=64, WRITE 573 MB
// vs 268 semantic, FETCH 156 MB, latency-bound at VALU 25%).
//   Block = 1024 threads (16 waves) = 16 sub-rows x all 8192 edge cols.
//   SWAPPED MFMA: D = mfma(A=edgeFrag, B=subFrag) -> D col (lane&15) is the
//   sub row; each lane owns ONE output row, 4 consecutive edge cols per acc.
//   tau/n/s1/s2 scalars; reduce = shfl_xor(16,32) + redS table, 1 barrier/it.
//   Scores: zh[64] packed fp16 (64 VGPR); __float2half_rn keeps numerics.
// ---------------------------------------------------------------------------
__global__
__attribute__((amdgpu_flat_work_group_size(1024, 1024), amdgpu_waves_per_eu(4, 4)))
void fused_score_entmax_kernel(
    const unsigned short* __restrict__ subE,
    const unsigned short* __restrict__ edgeE,
    const float* __restrict__ log_scale,
    float* __restrict__ out)
{
    const int t    = threadIdx.x;
    const int lane = t & 63;
    const int wid  = t >> 6;        // 0..15
    const int li   = lane & 15;     // sub-row owned by this lane
    const int quad = lane >> 4;     // 0..3
    const int r0   = blockIdx.x * 16;
    const int c0   = wid * 512;     // edge-col base of this wave

    __shared__ float4 redS[2][16][16];   // [buf][wave][row] = {n,s1,s2,-}

    // ---- B fragments: subE rows r0..r0+15, K=192 (all waves same 6 KB) ----
    short8 bf[6];
#pragma unroll
    for (int kk = 0; kk < 6; ++kk)
        bf[kk] = *(const short8*)(subE + (size_t)(r0 + li) * 192 + kk * 32 + quad * 8);

    float sc = expf(log_scale[0]);
    sc = fminf(fmaxf(sc, 0.5f), 20.0f);
    const float zs = sc * 0.5f;          // z = scores/2

    // ---- GEMM: 32 tiles/wave; acc[r] = (edge col c0+tp*16+quad*4+r, row li) ----
    unsigned int zh[64];                 // zh[tp*2+h]: cols quad*4+2h, +1 (packed fp16)

#pragma unroll
    for (int tp = 0; tp < 32; ++tp) {
        const unsigned short* ap = edgeE + (size_t)(c0 + tp * 16 + li) * 192 + quad * 8;
        float4v acc = (float4v){0.f, 0.f, 0.f, 0.f};
#pragma unroll
        for (int kk = 0; kk < 6; ++kk) {
            short8 af = *(const short8*)(ap + kk * 32);
            acc = __builtin_amdgcn_mfma_f32_16x16x32_bf16(af, bf[kk], acc, 0, 0, 0);
        }
        union { unsigned u; __half2 h2; } c01, c23;
        c01.h2.x = __float2half_rn(acc[0] * zs);
        c01.h2.y = __float2half_rn(acc[1] * zs);
        c23.h2.x = __float2half_rn(acc[2] * zs);
        c23.h2.y = __float2half_rn(acc[3] * zs);
        zh[tp * 2 + 0] = c01.u;
        zh[tp * 2 + 1] = c23.u;
    }

    // ---- row max -> tau0 = m - 1 (tau* is always in [m-1, m)) ----
    float m = -1e30f;
#pragma unroll
    for (int j = 0; j < 64; ++j) {
        union { unsigned u; __half2 h2; } cv; cv.u = zh[j];
        float2 f = __half22float2(cv.h2);
        m = fmaxf(m, fmaxf(f.x, f.y));
    }
    m = fmaxf(m, __shfl_xor(m, 16, 64));
    m = fmaxf(m, __shfl_xor(m, 32, 64));
    if (quad == 0) redS[0][wid][li] = (float4){m, 0.f, 0.f, 0.f};
    __syncthreads();
    {
        float mw = redS[0][quad * 4 + 0][li].x;
        mw = fmaxf(mw, redS[0][quad * 4 + 1][li].x);
        mw = fmaxf(mw, redS[0][quad * 4 + 2][li].x);
        mw = fmaxf(mw, redS[0][quad * 4 + 3][li].x);
        mw = fmaxf(mw, __shfl_xor(mw, 16, 64));
        mw = fmaxf(mw, __shfl_xor(mw, 32, 64));
        m = mw;
    }
    float tau = m - 1.0f;

    // ---- support-set iteration, exact quadratic solve, 1 barrier/iter ----
    int buf = 1;                         // iter 0 writes redS[1] (max used [0])
    for (int it = 0; it < ITERS; ++it) {
        float n = 0.f, s1 = 0.f, s2 = 0.f;
#pragma unroll
        for (int j = 0; j < 64; ++j) {
            union { unsigned u; __half2 h2; } cv; cv.u = zh[j];
            float2 f = __half22float2(cv.h2);
            {
                const bool  p  = f.x > tau;
                const float zm = p ? f.x : 0.f;
                n  += p ? 1.f : 0.f;
                s1 += zm;
                s2  = fmaf(zm, f.x, s2);
            }
            {
                const bool  p  = f.y > tau;
                const float zm = p ? f.y : 0.f;
                n  += p ? 1.f : 0.f;
                s1 += zm;
                s2  = fmaf(zm, f.y, s2);
            }
        }
        // combine the 4 lanes owning row li within this wave
        n  += __shfl_xor(n, 16, 64);  n  += __shfl_xor(n, 32, 64);
        s1 += __shfl_xor(s1, 16, 64); s1 += __shfl_xor(s1, 32, 64);
        s2 += __shfl_xor(s2, 16, 64); s2 += __shfl_xor(s2, 32, 64);
        if (quad == 0) redS[buf][wid][li] = (float4){n, s1, s2, 0.f};
        __syncthreads();

        // every lane gathers 4 waves' partials, combines quads via shfl
        float4 p0 = redS[buf][quad * 4 + 0][li];
        float4 p1 = redS[buf][quad * 4 + 1][li];
        float4 p2 = redS[buf][quad * 4 + 2][li];
        float4 p3 = redS[buf][quad * 4 + 3][li];
        float N  = p0.x + p1.x + p2.x + p3.x;
        float S1 = p0.y + p1.y + p2.y + p3.y;
        float S2 = p0.z + p1.z + p2.z + p3.z;
        N  += __shfl_xor(N, 16, 64);  N  += __shfl_xor(N, 32, 64);
        S1 += __shfl_xor(S1, 16, 64); S1 += __shfl_xor(S1, 32, 64);
        S2 += __shfl_xor(S2, 16, 64); S2 += __shfl_xor(S2, 32, 64);

        const float disc = S1 * S1 - N * (S2 - 1.0f);
        float tn;
        if (disc >= 0.0f) {
            tn = (S1 - sqrtf(disc)) / N;
        } else {
            const float g = S1 - N * tau;
            const float f = S2 - tau * (2.0f * S1 - N * tau);
            tn = tau + (f - 1.0f) / (2.0f * g);
        }
        const bool cf = (tn == tau);
        tau = tn;
        buf ^= 1;
        if (__all(cf)) break;            // identical in every wave
    }

    // ---- emit p = clip(z - tau, 0)^2, float4v nontemporal stores ----
    float* orow = out + (size_t)(r0 + li) * 8192 + c0;
#pragma unroll
    for (int tp = 0; tp < 32; ++tp) {
        union { unsigned u; __half2 h2; } c01, c23;
        c01.u = zh[tp * 2 + 0];
        c23.u = zh[tp * 2 + 1];
        float2 f01 = __half22float2(c01.h2);
        float2 f23 = __half22float2(c23.h2);
        float4v pv;
        float d;
        d = fmaxf(f01.x - tau, 0.f); pv.x = d * d;
        d = fmaxf(f01.y - tau, 0.f); pv.y = d * d;
        d = fmaxf(f23.x - tau, 0.f); pv.z = d * d;
        d = fmaxf(f23.y - tau, 0.f); pv.w = d * d;
        __builtin_nontemporal_store(pv, (float4v*)(orow + tp * 16 + quad * 4));
    }
}

// ---------------------------------------------------------------------------
extern "C" void kernel_launch(void* const* d_in, const int* in_sizes, int n_in,
                              void* d_out, int out_size, void* d_ws, size_t ws_size,
                              hipStream_t stream)
{
    const float* edge_repr = (const float*)d_in[0];
    const float* sub_repr  = (const float*)d_in[1];
    const float* W_sub     = (const float*)d_in[2];
    const float* b_sub     = (const float*)d_in[3];
    const float* W_edge    = (const float*)d_in[4];
    const float* b_edge    = (const float*)d_in[5];
    const float* log_scale = (const float*)d_in[6];
    float* out = (float*)d_out;

    unsigned short* subE  = (unsigned short*)d_ws;                 // 3 MB
    unsigned short* edgeE = subE + (size_t)8192 * 192;             // 3 MB

    proj_norm_kernel<<<dim3(256, 2), 256, 0, stream>>>(
        sub_repr, edge_repr, W_sub, b_sub, W_edge, b_edge, subE, edgeE);

    fused_score_entmax_kernel<<<dim3(512), 1024, 0, stream>>>(
        subE, edgeE, log_scale, out);
}

// Round 5
// 628.074 us; speedup vs baseline: 1.1973x; 1.1973x over previous
//
#include <hip/hip_runtime.h>
#include <hip/hip_fp16.h>
#include <math.h>

#define ITERS 12

typedef __attribute__((ext_vector_type(8))) short short8;
typedef __attribute__((ext_vector_type(4))) float float4v;

// AGPR park/unpark (gfx950 unified file: MFMA kernels get ~half the budget
// as AGPRs; scores live there so the arch-VGPR half never spills).
#define AWRITE(dst, src) \
    asm volatile("v_accvgpr_write_b32 %0, %1" : "=a"(dst) : "v"(src))
#define AREAD(dst, src) \
    asm volatile("v_accvgpr_read_b32 %0, %1" : "=v"(dst) : "a"(src))

static __device__ inline unsigned short f2bf(float f) {
    union { float f; unsigned int u; } c; c.f = f;
    unsigned int u = c.u;
    u += 0x7fffu + ((u >> 16) & 1u);          // round-to-nearest-even
    return (unsigned short)(u >> 16);
}
static __device__ inline float bf2f(unsigned short h) {
    union { float f; unsigned int u; } c; c.u = ((unsigned int)h) << 16;
    return c.f;
}

// ---------------------------------------------------------------------------
// Kernel A (unchanged): P = l2_normalize(X @ W^T + b), emitted as split-bf16
// rows of 192:
//   sub:  [hi(64) | lo(64) | hi(64)]
//   edge: [hi(64) | hi(64) | lo(64)]
// so that subE @ edgeE^T over K=192 = Ah*Bh + Al*Bh + Ah*Bl (lo*lo dropped).
// ---------------------------------------------------------------------------
__global__ __launch_bounds__(256) void proj_norm_kernel(
    const float* __restrict__ Xsub, const float* __restrict__ Xedge,
    const float* __restrict__ Wsub, const float* __restrict__ bsub,
    const float* __restrict__ Wedge, const float* __restrict__ bedge,
    unsigned short* __restrict__ subE, unsigned short* __restrict__ edgeE)
{
    const int mat = blockIdx.y;
    const float* X  = mat ? Xedge : Xsub;
    const float* W  = mat ? Wedge : Wsub;
    const float* Bv = mat ? bedge : bsub;
    unsigned short* OUT = mat ? edgeE : subE;

    const int r0 = blockIdx.x * 32;
    const int t  = threadIdx.x;
    const int tx = t & 15, ty = t >> 4;

    __shared__ float xs[64 * 34];   // [k][row(32)+pad]
    __shared__ float ws[64 * 68];   // [k][col(64)+pad]

    float acc[2][4] = {};

    for (int ch = 0; ch < 8; ++ch) {
        const int kb = ch * 64;
#pragma unroll
        for (int i = 0; i < 2; ++i) {
            int e = t + 256 * i;            // 512 float4 (32 rows x 16 kq)
            int row = e & 31, kq = e >> 5;
            float4 xv = *(const float4*)(X + (size_t)(r0 + row) * 512 + kb + kq * 4);
            xs[(kq * 4 + 0) * 34 + row] = xv.x;
            xs[(kq * 4 + 1) * 34 + row] = xv.y;
            xs[(kq * 4 + 2) * 34 + row] = xv.z;
            xs[(kq * 4 + 3) * 34 + row] = xv.w;
        }
#pragma unroll
        for (int i = 0; i < 4; ++i) {
            int e = t + 256 * i;            // 1024 float4 (64 cols x 16 kq)
            int col = e & 63, kq = e >> 6;
            float4 wv = *(const float4*)(W + (size_t)col * 512 + kb + kq * 4);
            ws[(kq * 4 + 0) * 68 + col] = wv.x;
            ws[(kq * 4 + 1) * 68 + col] = wv.y;
            ws[(kq * 4 + 2) * 68 + col] = wv.z;
            ws[(kq * 4 + 3) * 68 + col] = wv.w;
        }
        __syncthreads();
#pragma unroll 8
        for (int k = 0; k < 64; ++k) {
            const float2 a2 = *(const float2*)&xs[k * 34 + ty * 2];
            const float4 b4 = *(const float4*)&ws[k * 68 + tx * 4];
            acc[0][0] = fmaf(a2.x, b4.x, acc[0][0]);
            acc[0][1] = fmaf(a2.x, b4.y, acc[0][1]);
            acc[0][2] = fmaf(a2.x, b4.z, acc[0][2]);
            acc[0][3] = fmaf(a2.x, b4.w, acc[0][3]);
            acc[1][0] = fmaf(a2.y, b4.x, acc[1][0]);
            acc[1][1] = fmaf(a2.y, b4.y, acc[1][1]);
            acc[1][2] = fmaf(a2.y, b4.z, acc[1][2]);
            acc[1][3] = fmaf(a2.y, b4.w, acc[1][3]);
        }
        __syncthreads();
    }

    const float4 bb = *(const float4*)(Bv + tx * 4);
#pragma unroll
    for (int i = 0; i < 2; ++i) {
        acc[i][0] += bb.x; acc[i][1] += bb.y; acc[i][2] += bb.z; acc[i][3] += bb.w;
        float s = acc[i][0]*acc[i][0] + acc[i][1]*acc[i][1]
                + acc[i][2]*acc[i][2] + acc[i][3]*acc[i][3];
#pragma unroll
        for (int off = 1; off <= 8; off <<= 1)
            s += __shfl_xor(s, off, 64);
        const float inv = 1.0f / fmaxf(sqrtf(s), 1e-12f);

        unsigned short h[4], l[4];
#pragma unroll
        for (int j = 0; j < 4; ++j) {
            const float v = acc[i][j] * inv;
            h[j] = f2bf(v);
            l[j] = f2bf(v - bf2f(h[j]));
        }
        uint2 hp, lp;
        hp.x = (unsigned)h[0] | ((unsigned)h[1] << 16);
        hp.y = (unsigned)h[2] | ((unsigned)h[3] << 16);
        lp.x = (unsigned)l[0] | ((unsigned)l[1] << 16);
        lp.y = (unsigned)l[2] | ((unsigned)l[3] << 16);

        unsigned short* base = OUT + (size_t)(r0 + ty * 2 + i) * 192 + tx * 4;
        *(uint2*)(base)       = hp;
        *(uint2*)(base + 64)  = mat ? hp : lp;   // edge: hi ; sub: lo
        *(uint2*)(base + 128) = mat ? lp : hp;   // edge: lo ; sub: hi
    }
}

// ---------------------------------------------------------------------------
// Kernel F (v4): FUSED scores + entmax with scores parked in AGPRs.
//   Evidence r1/r3/r4: with MFMA present the gfx950 backend splits the
//   per-wave register budget ~evenly arch/AGPR (reported VGPR = budget/2 in
//   every round), so a >budget/2 arch demand spills no matter what the
//   attributes say.  Fix: USE the AGPR half.  512 threads (8 waves, budget
//   256 -> 128 arch + 128 AGPR).  Wave owns 1024 edge cols = 64 MFMA tiles
//   -> 128 packed-fp16 score words = exactly the 128 AGPRs, moved with
//   v_accvgpr_write/read asm ("a" constraints).  asm volatile on reads so
//   the loop-invariant unparks can't be hoisted out of the iteration loop.
//   SWAPPED MFMA (D col = sub row): each lane owns ONE row; tau/n/s1/s2
//   scalars, reduce = shfl_xor(16,32) + redS[2][8][16] table, 1 barrier/it.
//   Numerics identical to r3 (passed): __float2half_rn quantization, exact
//   quadratic tau solve, ITERS=12 with uniform early break.
// ---------------------------------------------------------------------------
__global__ __launch_bounds__(512, 2) void fused_score_entmax_kernel(
    const unsigned short* __restrict__ subE,
    const unsigned short* __restrict__ edgeE,
    const float* __restrict__ log_scale,
    float* __restrict__ out)
{
    const int t    = threadIdx.x;
    const int lane = t & 63;
    const int wid  = t >> 6;        // 0..7
    const int li   = lane & 15;     // sub-row owned by this lane
    const int quad = lane >> 4;     // 0..3
    const int r0   = blockIdx.x * 16;
    const int c0   = wid * 1024;    // edge-col base of this wave

    __shared__ float4 redS[2][8][16];   // [buf][wave][row] = {n,s1,s2,-}

    // ---- B fragments: subE rows r0..r0+15, K=192 (all waves same 6 KB) ----
    short8 bf[6];
#pragma unroll
    for (int kk = 0; kk < 6; ++kk)
        bf[kk] = *(const short8*)(subE + (size_t)(r0 + li) * 192 + kk * 32 + quad * 8);

    float sc = expf(log_scale[0]);
    sc = fminf(fmaxf(sc, 0.5f), 20.0f);
    const float zs = sc * 0.5f;          // z = scores/2

    // ---- GEMM: 64 tiles/wave; scores packed fp16 -> AGPRs zha[128] ----
    unsigned zha[128];                   // AGPR-resident (via AWRITE/AREAD)

#pragma unroll
    for (int tp = 0; tp < 64; ++tp) {
        const unsigned short* ap = edgeE + (size_t)(c0 + tp * 16 + li) * 192 + quad * 8;
        float4v acc = (float4v){0.f, 0.f, 0.f, 0.f};
#pragma unroll
        for (int kk = 0; kk < 6; ++kk) {
            short8 af = *(const short8*)(ap + kk * 32);
            acc = __builtin_amdgcn_mfma_f32_16x16x32_bf16(af, bf[kk], acc, 0, 0, 0);
        }
        union { unsigned u; __half2 h2; } c01, c23;
        c01.h2.x = __float2half_rn(acc[0] * zs);
        c01.h2.y = __float2half_rn(acc[1] * zs);
        c23.h2.x = __float2half_rn(acc[2] * zs);
        c23.h2.y = __float2half_rn(acc[3] * zs);
        AWRITE(zha[tp * 2 + 0], c01.u);
        AWRITE(zha[tp * 2 + 1], c23.u);
    }

    // ---- row max -> tau0 = m - 1 (tau* is always in [m-1, m)) ----
    float m = -1e30f;
#pragma unroll
    for (int j = 0; j < 128; ++j) {
        union { unsigned u; __half2 h2; } cv;
        AREAD(cv.u, zha[j]);
        float2 f = __half22float2(cv.h2);
        m = fmaxf(m, fmaxf(f.x, f.y));
    }
    m = fmaxf(m, __shfl_xor(m, 16, 64));
    m = fmaxf(m, __shfl_xor(m, 32, 64));
    if (quad == 0) redS[0][wid][li] = (float4){m, 0.f, 0.f, 0.f};
    __syncthreads();
    {
        float mw = fmaxf(redS[0][quad * 2 + 0][li].x, redS[0][quad * 2 + 1][li].x);
        mw = fmaxf(mw, __shfl_xor(mw, 16, 64));
        mw = fmaxf(mw, __shfl_xor(mw, 32, 64));
        m = mw;
    }
    float tau = m - 1.0f;

    // ---- support-set iteration, exact quadratic solve, 1 barrier/iter ----
    int buf = 1;                         // iter 0 writes redS[1] (max used [0])
    for (int it = 0; it < ITERS; ++it) {
        float n = 0.f, s1 = 0.f, s2 = 0.f;
#pragma unroll
        for (int j = 0; j < 128; ++j) {
            union { unsigned u; __half2 h2; } cv;
            AREAD(cv.u, zha[j]);
            float2 f = __half22float2(cv.h2);
            {
                const bool  p  = f.x > tau;
                const float zm = p ? f.x : 0.f;
                n  += p ? 1.f : 0.f;
                s1 += zm;
                s2  = fmaf(zm, f.x, s2);
            }
            {
                const bool  p  = f.y > tau;
                const float zm = p ? f.y : 0.f;
                n  += p ? 1.f : 0.f;
                s1 += zm;
                s2  = fmaf(zm, f.y, s2);
            }
        }
        // combine the 4 lanes owning row li within this wave
        n  += __shfl_xor(n, 16, 64);  n  += __shfl_xor(n, 32, 64);
        s1 += __shfl_xor(s1, 16, 64); s1 += __shfl_xor(s1, 32, 64);
        s2 += __shfl_xor(s2, 16, 64); s2 += __shfl_xor(s2, 32, 64);
        if (quad == 0) redS[buf][wid][li] = (float4){n, s1, s2, 0.f};
        __syncthreads();

        // every lane gathers 2 waves' partials, combines quads via shfl
        float4 pa = redS[buf][quad * 2 + 0][li];
        float4 pb = redS[buf][quad * 2 + 1][li];
        float N  = pa.x + pb.x;
        float S1 = pa.y + pb.y;
        float S2 = pa.z + pb.z;
        N  += __shfl_xor(N, 16, 64);  N  += __shfl_xor(N, 32, 64);
        S1 += __shfl_xor(S1, 16, 64); S1 += __shfl_xor(S1, 32, 64);
        S2 += __shfl_xor(S2, 16, 64); S2 += __shfl_xor(S2, 32, 64);

        const float disc = S1 * S1 - N * (S2 - 1.0f);
        float tn;
        if (disc >= 0.0f) {
            tn = (S1 - sqrtf(disc)) / N;
        } else {
            const float g = S1 - N * tau;
            const float f = S2 - tau * (2.0f * S1 - N * tau);
            tn = tau + (f - 1.0f) / (2.0f * g);
        }
        const bool cf = (tn == tau);
        tau = tn;
        buf ^= 1;
        if (__all(cf)) break;            // identical in every wave
    }

    // ---- emit p = clip(z - tau, 0)^2, float4v nontemporal stores ----
    float* orow = out + (size_t)(r0 + li) * 8192 + c0;
#pragma unroll
    for (int tp = 0; tp < 64; ++tp) {
        union { unsigned u; __half2 h2; } c01, c23;
        AREAD(c01.u, zha[tp * 2 + 0]);
        AREAD(c23.u, zha[tp * 2 + 1]);
        float2 f01 = __half22float2(c01.h2);
        float2 f23 = __half22float2(c23.h2);
        float4v pv;
        float d;
        d = fmaxf(f01.x - tau, 0.f); pv.x = d * d;
        d = fmaxf(f01.y - tau, 0.f); pv.y = d * d;
        d = fmaxf(f23.x - tau, 0.f); pv.z = d * d;
        d = fmaxf(f23.y - tau, 0.f); pv.w = d * d;
        __builtin_nontemporal_store(pv, (float4v*)(orow + tp * 16 + quad * 4));
    }
}

// ---------------------------------------------------------------------------
extern "C" void kernel_launch(void* const* d_in, const int* in_sizes, int n_in,
                              void* d_out, int out_size, void* d_ws, size_t ws_size,
                              hipStream_t stream)
{
    const float* edge_repr = (const float*)d_in[0];
    const float* sub_repr  = (const float*)d_in[1];
    const float* W_sub     = (const float*)d_in[2];
    const float* b_sub     = (const float*)d_in[3];
    const float* W_edge    = (const float*)d_in[4];
    const float* b_edge    = (const float*)d_in[5];
    const float* log_scale = (const float*)d_in[6];
    float* out = (float*)d_out;

    unsigned short* subE  = (unsigned short*)d_ws;                 // 3 MB
    unsigned short* edgeE = subE + (size_t)8192 * 192;             // 3 MB

    proj_norm_kernel<<<dim3(256, 2), 256, 0, stream>>>(
        sub_repr, edge_repr, W_sub, b_sub, W_edge, b_edge, subE, edgeE);

    fused_score_entmax_kernel<<<dim3(512), 512, 0, stream>>>(
        subE, edgeE, log_scale, out);
}